// Round 6
// baseline (5835.138 us; speedup 1.0000x reference)
//
#include <hip/hip_runtime.h>
#include <hip/hip_bf16.h>
#include <math.h>

#define T_STEPS 512
#define BATCH   64
#define IN_DIM  1024
#define HID     1024
#define BH_SZ   (BATCH * HID)

typedef short bf16x8 __attribute__((ext_vector_type(8)));
typedef float f32x4  __attribute__((ext_vector_type(4)));

// ---- coherent (agent-scope, cache-bypassing) scalar accessors -------------
__device__ __forceinline__ unsigned ld_coh_u32(const unsigned* p) {
    return __hip_atomic_load(p, __ATOMIC_RELAXED, __HIP_MEMORY_SCOPE_AGENT);
}
__device__ __forceinline__ void st_coh_u32(unsigned* p, unsigned v) {
    __hip_atomic_store(p, v, __ATOMIC_RELAXED, __HIP_MEMORY_SCOPE_AGENT);
}
__device__ __forceinline__ float ld_coh_f32(const float* p) {
    unsigned u = __hip_atomic_load((const unsigned*)p, __ATOMIC_RELAXED,
                                   __HIP_MEMORY_SCOPE_AGENT);
    return __builtin_bit_cast(float, u);
}
__device__ __forceinline__ void st_coh_f32(float* p, float v) {
    __hip_atomic_store((unsigned*)p, __builtin_bit_cast(unsigned, v),
                       __ATOMIC_RELAXED, __HIP_MEMORY_SCOPE_AGENT);
}

// ---- bf16 split helpers (RNE) ---------------------------------------------
__device__ __forceinline__ unsigned short f2bf(float x) {
    unsigned u = __builtin_bit_cast(unsigned, x);
    unsigned r = u + 0x7FFFu + ((u >> 16) & 1u);
    return (unsigned short)(r >> 16);
}
__device__ __forceinline__ float bf2f(unsigned short h) {
    unsigned u = ((unsigned)h) << 16;
    return __builtin_bit_cast(float, u);
}

// ---------------------------------------------------------------------------
// Kernel A: xp = input @ W_ih^T + b_ih + b_hh   (unchanged)
// ---------------------------------------------------------------------------
__global__ __launch_bounds__(256) void xproj_kernel(
    const float* __restrict__ A,
    const float* __restrict__ W,
    const float* __restrict__ b_ih,
    const float* __restrict__ b_hh,
    float* __restrict__ out)
{
    constexpr int BM = 128, BN = 64, BK = 32;
    __shared__ float As[BK][BM + 4];
    __shared__ float Bs[BK][BN + 4];

    const int n0 = blockIdx.x * BN;
    const int m0 = blockIdx.y * BM;
    const int tid = threadIdx.x;
    const int tx = tid & 15;
    const int ty = tid >> 4;

    float acc[8][4] = {};

    for (int k0 = 0; k0 < IN_DIM; k0 += BK) {
        #pragma unroll
        for (int i = 0; i < 4; i++) {
            int f4 = i * 256 + tid;
            int r = f4 >> 3, c4 = f4 & 7;
            float4 v = *(const float4*)(A + (long)(m0 + r) * IN_DIM + k0 + c4 * 4);
            As[c4 * 4 + 0][r] = v.x;
            As[c4 * 4 + 1][r] = v.y;
            As[c4 * 4 + 2][r] = v.z;
            As[c4 * 4 + 3][r] = v.w;
        }
        #pragma unroll
        for (int i = 0; i < 2; i++) {
            int f4 = i * 256 + tid;
            int r = f4 >> 3, c4 = f4 & 7;
            float4 v = *(const float4*)(W + (long)(n0 + r) * IN_DIM + k0 + c4 * 4);
            Bs[c4 * 4 + 0][r] = v.x;
            Bs[c4 * 4 + 1][r] = v.y;
            Bs[c4 * 4 + 2][r] = v.z;
            Bs[c4 * 4 + 3][r] = v.w;
        }
        __syncthreads();

        #pragma unroll 8
        for (int k = 0; k < BK; k++) {
            float4 a0 = *(const float4*)&As[k][ty * 8];
            float4 a1 = *(const float4*)&As[k][ty * 8 + 4];
            float4 bv = *(const float4*)&Bs[k][tx * 4];
            float av[8] = {a0.x, a0.y, a0.z, a0.w, a1.x, a1.y, a1.z, a1.w};
            float bb[4] = {bv.x, bv.y, bv.z, bv.w};
            #pragma unroll
            for (int i = 0; i < 8; i++)
                #pragma unroll
                for (int j = 0; j < 4; j++)
                    acc[i][j] += av[i] * bb[j];
        }
        __syncthreads();
    }

    float4 bi = *(const float4*)&b_ih[n0 + tx * 4];
    float4 bh = *(const float4*)&b_hh[n0 + tx * 4];
    float bsum[4] = {bi.x + bh.x, bi.y + bh.y, bi.z + bh.z, bi.w + bh.w};

    #pragma unroll
    for (int i = 0; i < 8; i++) {
        float4 o;
        o.x = acc[i][0] + bsum[0];
        o.y = acc[i][1] + bsum[1];
        o.z = acc[i][2] + bsum[2];
        o.w = acc[i][3] + bsum[3];
        *(float4*)(out + (long)(m0 + ty * 8 + i) * HID + n0 + tx * 4) = o;
    }
}

// ---------------------------------------------------------------------------
// Kernel B v6: MFMA (3-term bf16 split) dot + v3's replay-proven FULL-grid
// barrier (reverted from v5's group-local barrier, the suspected race).
// 256 blocks x 512 threads. Block tile 16b x 16j, wave k-range 128.
// ---------------------------------------------------------------------------
__global__ __launch_bounds__(512, 2) void rnn_kernel(
    const float* __restrict__ h0,
    const float* __restrict__ Whh,
    float* __restrict__ out,         // [T][B][H] xp in -> h out; h_last at end
    float* hcomm,                    // [2][B][H] coherent fp32 h exchange
    unsigned* flags)                 // [256*32] zeroed
{
    __shared__ unsigned short Whi[16 * 1024];
    __shared__ unsigned short Wlo[16 * 1024];
    __shared__ unsigned short Hhi[16 * 1024];
    __shared__ unsigned short Hlo[16 * 1024];
    __shared__ f32x4 Pred[8][64];

    const int bid = blockIdx.x;
    const int j0 = (bid & 63) * 16;
    const int b0 = (bid >> 6) * 16;
    const int tid  = threadIdx.x;
    const int lane = tid & 63;
    const int w    = tid >> 6;        // wave 0..7 -> k-range [w*128,(w+1)*128)

    // ---- stage W_hh rows j0..j0+15 as bf16 hi/lo, XOR-swizzled ----
    #pragma unroll
    for (int i = 0; i < 4; i++) {
        int c = i * 512 + tid;            // chunk of 8 elems
        int row = c >> 7;
        int k0 = (c & 127) * 8;
        const float* src = Whh + (size_t)(j0 + row) * HID + k0;
        float4 v0 = *(const float4*)(src);
        float4 v1 = *(const float4*)(src + 4);
        float vv[8] = {v0.x, v0.y, v0.z, v0.w, v1.x, v1.y, v1.z, v1.w};
        bf16x8 hi8, lo8;
        #pragma unroll
        for (int e = 0; e < 8; e++) {
            unsigned short h = f2bf(vv[e]);
            hi8[e] = (short)h;
            lo8[e] = (short)f2bf(vv[e] - bf2f(h));
        }
        int ofs = row * 1024 + (k0 ^ ((row & 7) << 3));
        *(bf16x8*)&Whi[ofs] = hi8;
        *(bf16x8*)&Wlo[ofs] = lo8;
    }

    const int o = tid;                 // tid<256: b = o>>4, j = o&15
    const size_t out_off = (size_t)(b0 + (o >> 4)) * HID + (size_t)(j0 + (o & 15));
    float xp_cur = (tid < 256) ? out[out_off] : 0.f;

    // fragment addressing: lane reads row (lane&15), 8 bf16 at k-base
    const int frow = lane & 15;
    const int ksub = (lane >> 4) * 8;          // 0,8,16,24
    const int sw   = (frow & 7) << 3;

    for (int t = 0; t < T_STEPS; t++) {
        // ---- stage h_{t-1} (16 rows), convert to bf16 hi/lo ----
        {
            const float* hsrc = (t == 0) ? h0
                              : hcomm + (size_t)((t + 1) & 1) * BH_SZ;
            #pragma unroll
            for (int i = 0; i < 4; i++) {
                int c = i * 512 + tid;
                int row = c >> 7;
                int k0 = (c & 127) * 8;
                const float* p = hsrc + (size_t)(b0 + row) * HID + k0;
                float vv[8];
                if (t == 0) {
                    float4 v0 = *(const float4*)(p);
                    float4 v1 = *(const float4*)(p + 4);
                    vv[0]=v0.x; vv[1]=v0.y; vv[2]=v0.z; vv[3]=v0.w;
                    vv[4]=v1.x; vv[5]=v1.y; vv[6]=v1.z; vv[7]=v1.w;
                } else {
                    #pragma unroll
                    for (int e = 0; e < 8; e++) vv[e] = ld_coh_f32(p + e);
                }
                bf16x8 hi8, lo8;
                #pragma unroll
                for (int e = 0; e < 8; e++) {
                    unsigned short h = f2bf(vv[e]);
                    hi8[e] = (short)h;
                    lo8[e] = (short)f2bf(vv[e] - bf2f(h));
                }
                int ofs = row * 1024 + (k0 ^ ((row & 7) << 3));
                *(bf16x8*)&Hhi[ofs] = hi8;
                *(bf16x8*)&Hlo[ofs] = lo8;
            }
        }
        __syncthreads();

        // ---- MFMA dot: wave w covers k in [w*128,(w+1)*128) ----
        {
            f32x4 acc = {0.f, 0.f, 0.f, 0.f};
            #pragma unroll
            for (int kk = 0; kk < 4; kk++) {
                int kidx = w * 128 + kk * 32 + ksub;       // full k index
                int ofs  = frow * 1024 + (kidx ^ sw);      // XOR after add
                bf16x8 ahi = *(const bf16x8*)&Hhi[ofs];
                bf16x8 alo = *(const bf16x8*)&Hlo[ofs];
                bf16x8 bhi = *(const bf16x8*)&Whi[ofs];
                bf16x8 blo = *(const bf16x8*)&Wlo[ofs];
                acc = __builtin_amdgcn_mfma_f32_16x16x32_bf16(ahi, bhi, acc, 0, 0, 0);
                acc = __builtin_amdgcn_mfma_f32_16x16x32_bf16(ahi, blo, acc, 0, 0, 0);
                acc = __builtin_amdgcn_mfma_f32_16x16x32_bf16(alo, bhi, acc, 0, 0, 0);
            }
            Pred[w][lane] = acc;   // D: col=lane&15 (j), rows (lane>>4)*4+r (b)
        }
        __syncthreads();

        // ---- reduce over 8 waves + tanh + store ----
        if (tid < 256) {
            const int b = o >> 4, j = o & 15;
            const int plane = ((b >> 2) << 4) | j;   // source lane in each wave
            const int pr = b & 3;                    // source reg
            float s = xp_cur;
            #pragma unroll
            for (int k = 0; k < 8; k++) s += Pred[k][plane][pr];
            float hn = tanhf(s);
            out[(size_t)t * BH_SZ + out_off] = hn;
            st_coh_f32(hcomm + (size_t)(t & 1) * BH_SZ + out_off, hn);
            if (t == T_STEPS - 1)
                out[(size_t)T_STEPS * BH_SZ + out_off] = hn;
        }
        __syncthreads();   // all threads' stores drained -> h globally visible

        // ---- arrive (own flag) ----
        if (tid == 0) st_coh_u32(&flags[bid * 32], (unsigned)(t + 1));

        // prefetch next xp under the poll
        float xp_next = 0.f;
        if (tid < 256 && t + 1 < T_STEPS)
            xp_next = out[(size_t)(t + 1) * BH_SZ + out_off];

        // ---- wait: FULL grid (v3 replay-proven) ----
        if (tid < 64) {
            const unsigned target = (unsigned)(t + 1);
            for (;;) {
                int ok = 1;
                #pragma unroll
                for (int g = 0; g < 4; g++) {
                    unsigned v = ld_coh_u32(&flags[(size_t)(tid + g * 64) * 32]);
                    ok &= (v >= target) ? 1 : 0;
                }
                if (__all(ok)) break;
                __builtin_amdgcn_s_sleep(1);
            }
        }
        __syncthreads();
        xp_cur = xp_next;
    }
}

// ---------------------------------------------------------------------------
extern "C" void kernel_launch(void* const* d_in, const int* in_sizes, int n_in,
                              void* d_out, int out_size, void* d_ws, size_t ws_size,
                              hipStream_t stream)
{
    const float* input  = (const float*)d_in[0];
    const float* hidden = (const float*)d_in[1];
    const float* W_ih   = (const float*)d_in[2];
    const float* W_hh   = (const float*)d_in[3];
    const float* b_ih   = (const float*)d_in[4];
    const float* b_hh   = (const float*)d_in[5];
    float* out = (float*)d_out;

    unsigned* flags = (unsigned*)d_ws;                         // 32 KB
    float* hcomm = (float*)((char*)d_ws + 256 * 32 * sizeof(unsigned));
    hipMemsetAsync(flags, 0, 256 * 32 * sizeof(unsigned), stream);

    dim3 gridA(HID / 64, (T_STEPS * BATCH) / 128, 1);
    xproj_kernel<<<gridA, 256, 0, stream>>>(input, W_ih, b_ih, b_hh, out);

    rnn_kernel<<<256, 512, 0, stream>>>(hidden, W_hh, out, hcomm, flags);
}

// Round 7
// 3141.756 us; speedup vs baseline: 1.8573x; 1.8573x over previous
//
#include <hip/hip_runtime.h>
#include <hip/hip_bf16.h>
#include <math.h>

#define T_STEPS 512
#define BATCH   64
#define IN_DIM  1024
#define HID     1024
#define BH_SZ   (BATCH * HID)

typedef short bf16x8 __attribute__((ext_vector_type(8)));
typedef float f32x4  __attribute__((ext_vector_type(4)));
typedef unsigned u32x4 __attribute__((ext_vector_type(4)));

// ---- coherent (agent-scope, cache-bypassing) accessors --------------------
__device__ __forceinline__ unsigned ld_coh_u32(const unsigned* p) {
    return __hip_atomic_load(p, __ATOMIC_RELAXED, __HIP_MEMORY_SCOPE_AGENT);
}
__device__ __forceinline__ void st_coh_u32(unsigned* p, unsigned v) {
    __hip_atomic_store(p, v, __ATOMIC_RELAXED, __HIP_MEMORY_SCOPE_AGENT);
}
__device__ __forceinline__ unsigned long long ld_coh_u64(const unsigned long long* p) {
    return __hip_atomic_load(p, __ATOMIC_RELAXED, __HIP_MEMORY_SCOPE_AGENT);
}

// ---- bf16 split helpers (RNE) ---------------------------------------------
__device__ __forceinline__ unsigned short f2bf(float x) {
    unsigned u = __builtin_bit_cast(unsigned, x);
    unsigned r = u + 0x7FFFu + ((u >> 16) & 1u);
    return (unsigned short)(r >> 16);
}
__device__ __forceinline__ float bf2f(unsigned short h) {
    unsigned u = ((unsigned)h) << 16;
    return __builtin_bit_cast(float, u);
}
__device__ __forceinline__ float fast_tanh(float x) {
    // 1 - 2/(e^{2x}+1); saturates to +/-1 correctly at extremes
    float e = __expf(2.0f * x);
    return 1.0f - 2.0f * __builtin_amdgcn_rcpf(e + 1.0f);
}

// ---------------------------------------------------------------------------
// Kernel A: xp = input @ W_ih^T + b_ih + b_hh   (unchanged)
// ---------------------------------------------------------------------------
__global__ __launch_bounds__(256) void xproj_kernel(
    const float* __restrict__ A,
    const float* __restrict__ W,
    const float* __restrict__ b_ih,
    const float* __restrict__ b_hh,
    float* __restrict__ out)
{
    constexpr int BM = 128, BN = 64, BK = 32;
    __shared__ float As[BK][BM + 4];
    __shared__ float Bs[BK][BN + 4];

    const int n0 = blockIdx.x * BN;
    const int m0 = blockIdx.y * BM;
    const int tid = threadIdx.x;
    const int tx = tid & 15;
    const int ty = tid >> 4;

    float acc[8][4] = {};

    for (int k0 = 0; k0 < IN_DIM; k0 += BK) {
        #pragma unroll
        for (int i = 0; i < 4; i++) {
            int f4 = i * 256 + tid;
            int r = f4 >> 3, c4 = f4 & 7;
            float4 v = *(const float4*)(A + (long)(m0 + r) * IN_DIM + k0 + c4 * 4);
            As[c4 * 4 + 0][r] = v.x;
            As[c4 * 4 + 1][r] = v.y;
            As[c4 * 4 + 2][r] = v.z;
            As[c4 * 4 + 3][r] = v.w;
        }
        #pragma unroll
        for (int i = 0; i < 2; i++) {
            int f4 = i * 256 + tid;
            int r = f4 >> 3, c4 = f4 & 7;
            float4 v = *(const float4*)(W + (long)(n0 + r) * IN_DIM + k0 + c4 * 4);
            Bs[c4 * 4 + 0][r] = v.x;
            Bs[c4 * 4 + 1][r] = v.y;
            Bs[c4 * 4 + 2][r] = v.z;
            Bs[c4 * 4 + 3][r] = v.w;
        }
        __syncthreads();

        #pragma unroll 8
        for (int k = 0; k < BK; k++) {
            float4 a0 = *(const float4*)&As[k][ty * 8];
            float4 a1 = *(const float4*)&As[k][ty * 8 + 4];
            float4 bv = *(const float4*)&Bs[k][tx * 4];
            float av[8] = {a0.x, a0.y, a0.z, a0.w, a1.x, a1.y, a1.z, a1.w};
            float bb[4] = {bv.x, bv.y, bv.z, bv.w};
            #pragma unroll
            for (int i = 0; i < 8; i++)
                #pragma unroll
                for (int j = 0; j < 4; j++)
                    acc[i][j] += av[i] * bb[j];
        }
        __syncthreads();
    }

    float4 bi = *(const float4*)&b_ih[n0 + tx * 4];
    float4 bh = *(const float4*)&b_hh[n0 + tx * 4];
    float bsum[4] = {bi.x + bh.x, bi.y + bh.y, bi.z + bh.z, bi.w + bh.w};

    #pragma unroll
    for (int i = 0; i < 8; i++) {
        float4 o;
        o.x = acc[i][0] + bsum[0];
        o.y = acc[i][1] + bsum[1];
        o.z = acc[i][2] + bsum[2];
        o.w = acc[i][3] + bsum[3];
        *(float4*)(out + (long)(m0 + ty * 8 + i) * HID + n0 + tx * 4) = o;
    }
}

// ---------------------------------------------------------------------------
// Kernel B v7: MFMA dot + producer-packed bf16 h exchange.
//  - producer packs (hi|lo<<16) u32, ONE coherent store per element
//  - consumer: 16 batched coherent u64 loads (load-only loop -> 1 IF round
//    trip), unpack 2 bit-ops/elem, LDS write
//  - out[] store moved after flag arrive (overlaps the poll)
//  - full-grid barrier skeleton identical to replay-proven v3/v6
// ---------------------------------------------------------------------------
__global__ __launch_bounds__(512, 2) void rnn_kernel(
    const float* __restrict__ h0,
    const float* __restrict__ Whh,
    float* __restrict__ out,         // [T][B][H] xp in -> h out; h_last at end
    unsigned* hcomm,                 // [2][B][H] packed bf16 hi/lo exchange
    unsigned* flags)                 // [256*32] zeroed
{
    __shared__ unsigned short Whi[16 * 1024];
    __shared__ unsigned short Wlo[16 * 1024];
    __shared__ unsigned short Hhi[16 * 1024];
    __shared__ unsigned short Hlo[16 * 1024];
    __shared__ f32x4 Pred[8][64];

    const int bid = blockIdx.x;
    const int j0 = (bid & 63) * 16;
    const int b0 = (bid >> 6) * 16;
    const int tid  = threadIdx.x;
    const int lane = tid & 63;
    const int w    = tid >> 6;        // wave 0..7 -> k-range [w*128,(w+1)*128)

    // ---- stage W_hh rows j0..j0+15 as bf16 hi/lo, XOR-swizzled ----
    #pragma unroll
    for (int i = 0; i < 4; i++) {
        int c = i * 512 + tid;            // chunk of 8 elems
        int row = c >> 7;
        int k0 = (c & 127) * 8;
        const float* src = Whh + (size_t)(j0 + row) * HID + k0;
        float4 v0 = *(const float4*)(src);
        float4 v1 = *(const float4*)(src + 4);
        float vv[8] = {v0.x, v0.y, v0.z, v0.w, v1.x, v1.y, v1.z, v1.w};
        bf16x8 hi8, lo8;
        #pragma unroll
        for (int e = 0; e < 8; e++) {
            unsigned short h = f2bf(vv[e]);
            hi8[e] = (short)h;
            lo8[e] = (short)f2bf(vv[e] - bf2f(h));
        }
        int ofs = row * 1024 + (k0 ^ ((row & 7) << 3));
        *(bf16x8*)&Whi[ofs] = hi8;
        *(bf16x8*)&Wlo[ofs] = lo8;
    }

    const int o = tid;                 // tid<256: b = o>>4, j = o&15
    const size_t out_off = (size_t)(b0 + (o >> 4)) * HID + (size_t)(j0 + (o & 15));
    float xp_cur = (tid < 256) ? out[out_off] : 0.f;

    // fragment addressing: lane reads row (lane&15), 8 bf16 at k-base
    const int frow = lane & 15;
    const int ksub = (lane >> 4) * 8;          // 0,8,16,24
    const int sw   = (frow & 7) << 3;

    for (int t = 0; t < T_STEPS; t++) {
        // ---- stage h_{t-1} (16 rows) into Hhi/Hlo ----
        if (t == 0) {
            #pragma unroll
            for (int i = 0; i < 4; i++) {
                int c = i * 512 + tid;
                int row = c >> 7;
                int k0 = (c & 127) * 8;
                const float* p = h0 + (size_t)(b0 + row) * HID + k0;
                float4 v0 = *(const float4*)(p);
                float4 v1 = *(const float4*)(p + 4);
                float vv[8] = {v0.x, v0.y, v0.z, v0.w, v1.x, v1.y, v1.z, v1.w};
                bf16x8 hi8, lo8;
                #pragma unroll
                for (int e = 0; e < 8; e++) {
                    unsigned short h = f2bf(vv[e]);
                    hi8[e] = (short)h;
                    lo8[e] = (short)f2bf(vv[e] - bf2f(h));
                }
                int ofs = row * 1024 + (k0 ^ ((row & 7) << 3));
                *(bf16x8*)&Hhi[ofs] = hi8;
                *(bf16x8*)&Hlo[ofs] = lo8;
            }
        } else {
            const unsigned long long* hsrc64 =
                (const unsigned long long*)(hcomm + (size_t)((t + 1) & 1) * BH_SZ);
            // load-only loop: 16 relaxed-atomic u64 loads, no intervening
            // stores -> issued back-to-back, ONE IF round trip
            unsigned long long pv[16];
            #pragma unroll
            for (int i = 0; i < 4; i++) {
                int c = i * 512 + tid;
                int row = c >> 7;
                int k0 = (c & 127) * 8;
                const unsigned long long* p =
                    hsrc64 + (((size_t)(b0 + row) * HID + k0) >> 1);
                #pragma unroll
                for (int e = 0; e < 4; e++)
                    pv[i * 4 + e] = ld_coh_u64(p + e);
            }
            // unpack + LDS write
            #pragma unroll
            for (int i = 0; i < 4; i++) {
                int c = i * 512 + tid;
                int row = c >> 7;
                int k0 = (c & 127) * 8;
                u32x4 hiu, lou;
                #pragma unroll
                for (int e = 0; e < 4; e++) {
                    unsigned long long q = pv[i * 4 + e];
                    unsigned p0 = (unsigned)q;
                    unsigned p1 = (unsigned)(q >> 32);
                    hiu[e] = (p0 & 0xFFFFu) | (p1 << 16);
                    lou[e] = (p0 >> 16) | (p1 & 0xFFFF0000u);
                }
                int ofs = row * 1024 + (k0 ^ ((row & 7) << 3));
                *(u32x4*)&Hhi[ofs] = hiu;
                *(u32x4*)&Hlo[ofs] = lou;
            }
        }
        __syncthreads();

        // ---- MFMA dot: wave w covers k in [w*128,(w+1)*128) ----
        {
            f32x4 acc = {0.f, 0.f, 0.f, 0.f};
            #pragma unroll
            for (int kk = 0; kk < 4; kk++) {
                int kidx = w * 128 + kk * 32 + ksub;       // full k index
                int ofs  = frow * 1024 + (kidx ^ sw);      // XOR after add
                bf16x8 ahi = *(const bf16x8*)&Hhi[ofs];
                bf16x8 alo = *(const bf16x8*)&Hlo[ofs];
                bf16x8 bhi = *(const bf16x8*)&Whi[ofs];
                bf16x8 blo = *(const bf16x8*)&Wlo[ofs];
                acc = __builtin_amdgcn_mfma_f32_16x16x32_bf16(ahi, bhi, acc, 0, 0, 0);
                acc = __builtin_amdgcn_mfma_f32_16x16x32_bf16(ahi, blo, acc, 0, 0, 0);
                acc = __builtin_amdgcn_mfma_f32_16x16x32_bf16(alo, bhi, acc, 0, 0, 0);
            }
            Pred[w][lane] = acc;   // D: col=lane&15 (j), rows (lane>>4)*4+r (b)
        }
        __syncthreads();

        // ---- reduce + tanh; coherent store ONLY (critical path) ----
        float hn = 0.f;
        if (tid < 256) {
            const int b = o >> 4, j = o & 15;
            const int plane = ((b >> 2) << 4) | j;   // source lane in each wave
            const int pr = b & 3;                    // source reg
            float s = xp_cur;
            #pragma unroll
            for (int k = 0; k < 8; k++) s += Pred[k][plane][pr];
            hn = fast_tanh(s);
            unsigned short hi = f2bf(hn);
            unsigned short lo = f2bf(hn - bf2f(hi));
            unsigned pk = (unsigned)hi | ((unsigned)lo << 16);
            st_coh_u32(hcomm + (size_t)(t & 1) * BH_SZ + out_off, pk);
        }
        __syncthreads();   // drains every thread's coherent h store

        // ---- arrive ----
        if (tid == 0) st_coh_u32(&flags[bid * 32], (unsigned)(t + 1));

        // ---- off-critical-path work overlapping the poll ----
        if (tid < 256) {
            out[(size_t)t * BH_SZ + out_off] = hn;       // cached, own cell
            if (t == T_STEPS - 1)
                out[(size_t)T_STEPS * BH_SZ + out_off] = hn;
        }
        float xp_next = 0.f;
        if (tid < 256 && t + 1 < T_STEPS)
            xp_next = out[(size_t)(t + 1) * BH_SZ + out_off];

        // ---- wait: FULL grid (replay-proven) ----
        if (tid < 64) {
            const unsigned target = (unsigned)(t + 1);
            for (;;) {
                int ok = 1;
                #pragma unroll
                for (int g = 0; g < 4; g++) {
                    unsigned v = ld_coh_u32(&flags[(size_t)(tid + g * 64) * 32]);
                    ok &= (v >= target) ? 1 : 0;
                }
                if (__all(ok)) break;
                __builtin_amdgcn_s_sleep(1);
            }
        }
        __syncthreads();
        xp_cur = xp_next;
    }
}

// ---------------------------------------------------------------------------
extern "C" void kernel_launch(void* const* d_in, const int* in_sizes, int n_in,
                              void* d_out, int out_size, void* d_ws, size_t ws_size,
                              hipStream_t stream)
{
    const float* input  = (const float*)d_in[0];
    const float* hidden = (const float*)d_in[1];
    const float* W_ih   = (const float*)d_in[2];
    const float* W_hh   = (const float*)d_in[3];
    const float* b_ih   = (const float*)d_in[4];
    const float* b_hh   = (const float*)d_in[5];
    float* out = (float*)d_out;

    unsigned* flags = (unsigned*)d_ws;                         // 32 KB
    unsigned* hcomm = (unsigned*)((char*)d_ws + 256 * 32 * sizeof(unsigned));
    hipMemsetAsync(flags, 0, 256 * 32 * sizeof(unsigned), stream);

    dim3 gridA(HID / 64, (T_STEPS * BATCH) / 128, 1);
    xproj_kernel<<<gridA, 256, 0, stream>>>(input, W_ih, b_ih, b_hh, out);

    rnn_kernel<<<256, 512, 0, stream>>>(hidden, W_hh, out, hcomm, flags);
}